// Round 5
// baseline (36158.585 us; speedup 1.0000x reference)
//
#include <hip/hip_runtime.h>
#include <hip/hip_bf16.h>

#define T_SEQ   2048
#define HIDDEN  2048
#define NH      32
#define NKV     8
#define HD      64
#define QKV_N   ((NH + 2*NKV) * HD)   // 3072
#define Q_COLS  (NH * HD)             // 2048
#define K_OFF   Q_COLS                // 2048
#define V_OFF   (Q_COLS + NKV * HD)   // 2560
#define SM_SCALE 0.125f               // 64^-0.5
#define ROPE_THETA 500000.0f

// ---------------------------------------------------------------------------
// GEMM: C[M,N] = A[M,K] * B[N,K]^T   (both row-major, K contiguous — "NT")
// 128x128 tile, BK=16, 256 threads, 8x8 micro-tile per thread (split 4+4).
// Register-prefetch double buffer (T14 async-stage split).
// ---------------------------------------------------------------------------
__global__ __launch_bounds__(256)
void gemm_nt(const float* __restrict__ A, const float* __restrict__ B,
             float* __restrict__ C, int M, int N, int K) {
    __shared__ float As[16][128 + 4];
    __shared__ float Bs[16][128 + 4];

    const int tid = threadIdx.x;
    const int m0 = blockIdx.y * 128;
    const int n0 = blockIdx.x * 128;
    const int tx = tid & 15;           // col fragment group
    const int ty = tid >> 4;           // row fragment group
    const int lr = tid >> 1;           // staging: row within tile (0..127)
    const int lc = (tid & 1) * 8;      // staging: k-col base (0 or 8)

    float c[8][8] = {};

    const float* Arow = A + (size_t)(m0 + lr) * K + lc;
    const float* Brow = B + (size_t)(n0 + lr) * K + lc;

    // prefetch K-tile 0 into registers
    float4 a0 = *(const float4*)&Arow[0];
    float4 a1 = *(const float4*)&Arow[4];
    float4 b0 = *(const float4*)&Brow[0];
    float4 b1 = *(const float4*)&Brow[4];

    for (int k0 = 0; k0 < K; k0 += 16) {
        As[lc + 0][lr] = a0.x; As[lc + 1][lr] = a0.y;
        As[lc + 2][lr] = a0.z; As[lc + 3][lr] = a0.w;
        As[lc + 4][lr] = a1.x; As[lc + 5][lr] = a1.y;
        As[lc + 6][lr] = a1.z; As[lc + 7][lr] = a1.w;
        Bs[lc + 0][lr] = b0.x; Bs[lc + 1][lr] = b0.y;
        Bs[lc + 2][lr] = b0.z; Bs[lc + 3][lr] = b0.w;
        Bs[lc + 4][lr] = b1.x; Bs[lc + 5][lr] = b1.y;
        Bs[lc + 6][lr] = b1.z; Bs[lc + 7][lr] = b1.w;
        __syncthreads();

        if (k0 + 16 < K) {             // issue next K-tile's loads early
            a0 = *(const float4*)&Arow[k0 + 16];
            a1 = *(const float4*)&Arow[k0 + 20];
            b0 = *(const float4*)&Brow[k0 + 16];
            b1 = *(const float4*)&Brow[k0 + 20];
        }

        #pragma unroll
        for (int k = 0; k < 16; ++k) {
            const float4 av0 = *(const float4*)&As[k][ty * 4];
            const float4 av1 = *(const float4*)&As[k][64 + ty * 4];
            const float4 bv0 = *(const float4*)&Bs[k][tx * 4];
            const float4 bv1 = *(const float4*)&Bs[k][64 + tx * 4];
            const float am[8] = {av0.x, av0.y, av0.z, av0.w,
                                 av1.x, av1.y, av1.z, av1.w};
            const float bm[8] = {bv0.x, bv0.y, bv0.z, bv0.w,
                                 bv1.x, bv1.y, bv1.z, bv1.w};
            #pragma unroll
            for (int i = 0; i < 8; ++i)
                #pragma unroll
                for (int j = 0; j < 8; ++j)
                    c[i][j] = fmaf(am[i], bm[j], c[i][j]);
        }
        __syncthreads();
    }

    #pragma unroll
    for (int i = 0; i < 8; ++i) {
        const int row = m0 + ((i < 4) ? (ty * 4 + i) : (64 + ty * 4 + i - 4));
        float4 v0 = make_float4(c[i][0], c[i][1], c[i][2], c[i][3]);
        float4 v1 = make_float4(c[i][4], c[i][5], c[i][6], c[i][7]);
        *(float4*)&C[(size_t)row * N + n0 + tx * 4]      = v0;
        *(float4*)&C[(size_t)row * N + n0 + 64 + tx * 4] = v1;
    }
}

// ---------------------------------------------------------------------------
// RoPE (neox rotate-half) applied in-place to q (heads 0..31) and k (32..39).
// ---------------------------------------------------------------------------
__global__ __launch_bounds__(256)
void rope_kernel(float* __restrict__ qkv, const int* __restrict__ positions) {
    int idx = blockIdx.x * blockDim.x + threadIdx.x;
    if (idx >= T_SEQ * 40 * 32) return;
    const int i  = idx & 31;            // rotary pair index 0..31
    const int hc = (idx >> 5) % 40;     // head-column 0..39 (q then k)
    const int t  = idx / (40 * 32);

    const float pos = (float)positions[t];
    const float expo = (float)(2 * i) / 64.f;
    const float inv_freq = __powf(ROPE_THETA, -expo);
    const float ang = pos * inv_freq;
    float sv, cv;
    sincosf(ang, &sv, &cv);

    float* p = qkv + (size_t)t * QKV_N + hc * HD + i;
    const float x1 = p[0];
    const float x2 = p[32];
    p[0]  = x1 * cv - x2 * sv;
    p[32] = x2 * cv + x1 * sv;
}

// ---------------------------------------------------------------------------
// Causal GQA flash attention, fp32 — load-balanced.
// Block = 32 q rows x one kv head; 128 threads = 2 waves = 4 q heads x 32
// rows (tid>>5 = head-in-group, tid&31 = row). K/V staged once in LDS for
// all 4 heads. Register-prefetch double buffer (T14).
// grid = (64, NKV); heavy blocks (large qb) dispatched FIRST via reversal
// so greedy CU scheduling packs the causal-imbalance tail.
// ---------------------------------------------------------------------------
__global__ __launch_bounds__(128)
void attn_fp32(const float* __restrict__ qkv, float* __restrict__ out) {
    __shared__ float Ks[32][64];
    __shared__ float Vs[32][64];

    const int tid = threadIdx.x;
    const int row = tid & 31;           // q row within block
    const int hs  = tid >> 5;           // head within kv group 0..3
    const int qb  = 63 - (int)blockIdx.x;  // heavy-first dispatch
    const int kvh = blockIdx.y;
    const int h   = kvh * 4 + hs;
    const int t   = qb * 32 + row;      // this thread's q row

    const float* qrow = qkv + (size_t)t * QKV_N + h * HD;
    float4 q4[16];
    #pragma unroll
    for (int i = 0; i < 16; ++i) q4[i] = *(const float4*)&qrow[i * 4];

    float4 o4[16] = {};
    float m = -3.0e38f, l = 0.f;

    // staging geometry: 32x64 tile, 128 threads, 4 float4 each for K,V
    const int sr = tid >> 2;            // row 0..31
    const int sc = (tid & 3) * 16;      // col 0,16,32,48
    const float* Kg = qkv + K_OFF + kvh * HD;
    const float* Vg = qkv + V_OFF + kvh * HD;

    const int ntiles = qb + 1;          // 32-key tiles covering <= qb*32+31

    float4 pk[4], pv[4];

    // stage tile 0
    {
        const size_t g = (size_t)sr * QKV_N + sc;
        #pragma unroll
        for (int i = 0; i < 4; ++i) {
            pk[i] = *(const float4*)&Kg[g + 4 * i];
            pv[i] = *(const float4*)&Vg[g + 4 * i];
        }
        #pragma unroll
        for (int i = 0; i < 4; ++i) {
            *(float4*)&Ks[sr][sc + 4 * i] = pk[i];
            *(float4*)&Vs[sr][sc + 4 * i] = pv[i];
        }
    }

    for (int kt = 0; kt < ntiles; ++kt) {
        __syncthreads();                // LDS writes for tile kt visible

        if (kt + 1 < ntiles) {          // issue next tile's loads early
            const size_t g = (size_t)((kt + 1) * 32 + sr) * QKV_N + sc;
            #pragma unroll
            for (int i = 0; i < 4; ++i) {
                pk[i] = *(const float4*)&Kg[g + 4 * i];
                pv[i] = *(const float4*)&Vg[g + 4 * i];
            }
        }

        {
            const bool masked = (kt == qb);   // only the diagonal tile masks
            float s[32];
            #pragma unroll
            for (int j = 0; j < 32; ++j) {
                const float4* kr = (const float4*)&Ks[j][0];
                float acc = 0.f;
                #pragma unroll
                for (int ii = 0; ii < 16; ++ii) {
                    const float4 kx = kr[ii];
                    const float4 qx = q4[ii];
                    acc = fmaf(qx.x, kx.x, acc);
                    acc = fmaf(qx.y, kx.y, acc);
                    acc = fmaf(qx.z, kx.z, acc);
                    acc = fmaf(qx.w, kx.w, acc);
                }
                s[j] = (!masked || j <= row) ? acc * SM_SCALE : -3.0e38f;
            }

            float mnew = m;
            #pragma unroll
            for (int j = 0; j < 32; ++j) mnew = fmaxf(mnew, s[j]);

            const float corr = __expf(m - mnew);   // first tile: exp(-huge)=0
            l *= corr;
            #pragma unroll
            for (int i = 0; i < 16; ++i) {
                o4[i].x *= corr; o4[i].y *= corr;
                o4[i].z *= corr; o4[i].w *= corr;
            }

            #pragma unroll
            for (int j = 0; j < 32; ++j) {
                const float p = __expf(s[j] - mnew);
                l += p;
                const float4* vr = (const float4*)&Vs[j][0];
                #pragma unroll
                for (int ii = 0; ii < 16; ++ii) {
                    const float4 vx = vr[ii];
                    o4[ii].x = fmaf(p, vx.x, o4[ii].x);
                    o4[ii].y = fmaf(p, vx.y, o4[ii].y);
                    o4[ii].z = fmaf(p, vx.z, o4[ii].z);
                    o4[ii].w = fmaf(p, vx.w, o4[ii].w);
                }
            }
            m = mnew;
        }

        __syncthreads();                // all waves done with tile kt

        if (kt + 1 < ntiles) {          // commit prefetched tile kt+1
            #pragma unroll
            for (int i = 0; i < 4; ++i) {
                *(float4*)&Ks[sr][sc + 4 * i] = pk[i];
                *(float4*)&Vs[sr][sc + 4 * i] = pv[i];
            }
        }
    }

    const float inv = 1.f / l;
    float* orow = out + (size_t)t * Q_COLS + h * HD;
    #pragma unroll
    for (int i = 0; i < 16; ++i) {
        float4 v = o4[i];
        v.x *= inv; v.y *= inv; v.z *= inv; v.w *= inv;
        *(float4*)&orow[i * 4] = v;
    }
}

// ---------------------------------------------------------------------------
extern "C" void kernel_launch(void* const* d_in, const int* in_sizes, int n_in,
                              void* d_out, int out_size, void* d_ws, size_t ws_size,
                              hipStream_t stream) {
    const float* hidden    = (const float*)d_in[0];
    const int*   positions = (const int*)d_in[1];
    const float* w_qkv     = (const float*)d_in[2];
    const float* w_o       = (const float*)d_in[3];
    float* out = (float*)d_out;

    float* qkv  = (float*)d_ws;                          // [T, 3072] 25.2 MB
    float* attn = qkv + (size_t)T_SEQ * QKV_N;           // [T, 2048] 16.8 MB

    // 1) QKV projection: qkv = hidden @ w_qkv^T
    gemm_nt<<<dim3(QKV_N / 128, T_SEQ / 128), 256, 0, stream>>>(
        hidden, w_qkv, qkv, T_SEQ, QKV_N, HIDDEN);

    // 2) RoPE on q and k, in place
    rope_kernel<<<(T_SEQ * 40 * 32 + 255) / 256, 256, 0, stream>>>(qkv, positions);

    // 3) causal GQA attention -> attn [T, NH*HD]
    attn_fp32<<<dim3(T_SEQ / 32, NKV), 128, 0, stream>>>(qkv, attn);

    // 4) output projection: out = attn @ w_o^T
    gemm_nt<<<dim3(HIDDEN / 128, T_SEQ / 128), 256, 0, stream>>>(
        attn, w_o, out, T_SEQ, HIDDEN, Q_COLS);
}

// Round 6
// 11295.276 us; speedup vs baseline: 3.2012x; 3.2012x over previous
//
#include <hip/hip_runtime.h>
#include <hip/hip_bf16.h>

#define T_SEQ   2048
#define HIDDEN  2048
#define NH      32
#define NKV     8
#define HD      64
#define QKV_N   ((NH + 2*NKV) * HD)   // 3072
#define Q_COLS  (NH * HD)             // 2048
#define K_OFF   Q_COLS                // 2048
#define V_OFF   (Q_COLS + NKV * HD)   // 2560
#define SM_SCALE 0.125f               // 64^-0.5
#define ROPE_THETA 500000.0f

// ---------------------------------------------------------------------------
// GEMM: C[M,N] = A[M,K] * B[N,K]^T   (both row-major, K contiguous — "NT")
// 128x128 tile, BK=16, 256 threads, 8x8 micro-tile per thread (split 4+4).
// Register-prefetch double buffer (T14 async-stage split).
// ---------------------------------------------------------------------------
__global__ __launch_bounds__(256)
void gemm_nt(const float* __restrict__ A, const float* __restrict__ B,
             float* __restrict__ C, int M, int N, int K) {
    __shared__ float As[16][128 + 4];
    __shared__ float Bs[16][128 + 4];

    const int tid = threadIdx.x;
    const int m0 = blockIdx.y * 128;
    const int n0 = blockIdx.x * 128;
    const int tx = tid & 15;           // col fragment group
    const int ty = tid >> 4;           // row fragment group
    const int lr = tid >> 1;           // staging: row within tile (0..127)
    const int lc = (tid & 1) * 8;      // staging: k-col base (0 or 8)

    float c[8][8] = {};

    const float* Arow = A + (size_t)(m0 + lr) * K + lc;
    const float* Brow = B + (size_t)(n0 + lr) * K + lc;

    // prefetch K-tile 0 into registers
    float4 a0 = *(const float4*)&Arow[0];
    float4 a1 = *(const float4*)&Arow[4];
    float4 b0 = *(const float4*)&Brow[0];
    float4 b1 = *(const float4*)&Brow[4];

    for (int k0 = 0; k0 < K; k0 += 16) {
        As[lc + 0][lr] = a0.x; As[lc + 1][lr] = a0.y;
        As[lc + 2][lr] = a0.z; As[lc + 3][lr] = a0.w;
        As[lc + 4][lr] = a1.x; As[lc + 5][lr] = a1.y;
        As[lc + 6][lr] = a1.z; As[lc + 7][lr] = a1.w;
        Bs[lc + 0][lr] = b0.x; Bs[lc + 1][lr] = b0.y;
        Bs[lc + 2][lr] = b0.z; Bs[lc + 3][lr] = b0.w;
        Bs[lc + 4][lr] = b1.x; Bs[lc + 5][lr] = b1.y;
        Bs[lc + 6][lr] = b1.z; Bs[lc + 7][lr] = b1.w;
        __syncthreads();

        if (k0 + 16 < K) {             // issue next K-tile's loads early
            a0 = *(const float4*)&Arow[k0 + 16];
            a1 = *(const float4*)&Arow[k0 + 20];
            b0 = *(const float4*)&Brow[k0 + 16];
            b1 = *(const float4*)&Brow[k0 + 20];
        }

        #pragma unroll
        for (int k = 0; k < 16; ++k) {
            const float4 av0 = *(const float4*)&As[k][ty * 4];
            const float4 av1 = *(const float4*)&As[k][64 + ty * 4];
            const float4 bv0 = *(const float4*)&Bs[k][tx * 4];
            const float4 bv1 = *(const float4*)&Bs[k][64 + tx * 4];
            const float am[8] = {av0.x, av0.y, av0.z, av0.w,
                                 av1.x, av1.y, av1.z, av1.w};
            const float bm[8] = {bv0.x, bv0.y, bv0.z, bv0.w,
                                 bv1.x, bv1.y, bv1.z, bv1.w};
            #pragma unroll
            for (int i = 0; i < 8; ++i)
                #pragma unroll
                for (int j = 0; j < 8; ++j)
                    c[i][j] = fmaf(am[i], bm[j], c[i][j]);
        }
        __syncthreads();
    }

    #pragma unroll
    for (int i = 0; i < 8; ++i) {
        const int row = m0 + ((i < 4) ? (ty * 4 + i) : (64 + ty * 4 + i - 4));
        float4 v0 = make_float4(c[i][0], c[i][1], c[i][2], c[i][3]);
        float4 v1 = make_float4(c[i][4], c[i][5], c[i][6], c[i][7]);
        *(float4*)&C[(size_t)row * N + n0 + tx * 4]      = v0;
        *(float4*)&C[(size_t)row * N + n0 + 64 + tx * 4] = v1;
    }
}

// ---------------------------------------------------------------------------
// RoPE (neox rotate-half) applied in-place to q (heads 0..31) and k (32..39).
// ---------------------------------------------------------------------------
__global__ __launch_bounds__(256)
void rope_kernel(float* __restrict__ qkv, const int* __restrict__ positions) {
    int idx = blockIdx.x * blockDim.x + threadIdx.x;
    if (idx >= T_SEQ * 40 * 32) return;
    const int i  = idx & 31;            // rotary pair index 0..31
    const int hc = (idx >> 5) % 40;     // head-column 0..39 (q then k)
    const int t  = idx / (40 * 32);

    const float pos = (float)positions[t];
    const float expo = (float)(2 * i) / 64.f;
    const float inv_freq = __powf(ROPE_THETA, -expo);
    const float ang = pos * inv_freq;
    float sv, cv;
    sincosf(ang, &sv, &cv);

    float* p = qkv + (size_t)t * QKV_N + hc * HD + i;
    const float x1 = p[0];
    const float x2 = p[32];
    p[0]  = x1 * cv - x2 * sv;
    p[32] = x2 * cv + x1 * sv;
}

// ---------------------------------------------------------------------------
// Causal GQA flash attention, fp32 — register-pressure-safe (no spills).
// Block = 32 q rows x one kv head; 256 threads = 4 waves = 4 q heads.
// Within a wave: lane = row + 32*half; the lane pair (L, L^32) shares a q
// row, each owning 32 of the 64 head dims. Score = partial dot +
// __shfl_xor(.,32). Per-thread state: q 8xfloat4 + o 8xfloat4 + s[32] +
// prefetch ≈ 130 VGPR (vs 256+spill before).
// K/V staged once in LDS for all 4 heads; reg-prefetch double buffer (T14).
// grid = (64, NKV); heavy blocks (large qb) first for causal load balance.
// ---------------------------------------------------------------------------
__global__ __launch_bounds__(256)
void attn_fp32(const float* __restrict__ qkv, float* __restrict__ out) {
    __shared__ float Ks[32][64];
    __shared__ float Vs[32][64];

    const int tid  = threadIdx.x;
    const int lane = tid & 63;
    const int wv   = tid >> 6;          // wave id 0..3 = head-in-group
    const int row  = lane & 31;         // q row within block
    const int half = lane >> 5;         // 0: dims 0-31, 1: dims 32-63
    const int qb   = 63 - (int)blockIdx.x;  // heavy-first dispatch
    const int kvh  = blockIdx.y;
    const int h    = kvh * 4 + wv;
    const int t    = qb * 32 + row;     // this thread's q row

    // q fragment: this half's 32 dims
    const float* qrow = qkv + (size_t)t * QKV_N + h * HD + half * 32;
    float4 q4[8];
    #pragma unroll
    for (int i = 0; i < 8; ++i) q4[i] = *(const float4*)&qrow[i * 4];

    float4 o4[8] = {};
    float m = -3.0e38f, l = 0.f;

    // staging: 32x64 tile, 256 threads, 2 float4 each for K and V
    const int sr = tid >> 3;            // row 0..31
    const int sc = (tid & 7) * 8;       // col 0,8,...,56
    const float* Kg = qkv + K_OFF + kvh * HD;
    const float* Vg = qkv + V_OFF + kvh * HD;

    const int ntiles = qb + 1;          // 32-key tiles covering <= qb*32+31

    float4 pk0, pk1, pv0, pv1;

    // stage tile 0
    {
        const size_t g = (size_t)sr * QKV_N + sc;
        pk0 = *(const float4*)&Kg[g];
        pk1 = *(const float4*)&Kg[g + 4];
        pv0 = *(const float4*)&Vg[g];
        pv1 = *(const float4*)&Vg[g + 4];
        *(float4*)&Ks[sr][sc]     = pk0;
        *(float4*)&Ks[sr][sc + 4] = pk1;
        *(float4*)&Vs[sr][sc]     = pv0;
        *(float4*)&Vs[sr][sc + 4] = pv1;
    }

    for (int kt = 0; kt < ntiles; ++kt) {
        __syncthreads();                // LDS writes for tile kt visible

        if (kt + 1 < ntiles) {          // issue next tile's loads early
            const size_t g = (size_t)((kt + 1) * 32 + sr) * QKV_N + sc;
            pk0 = *(const float4*)&Kg[g];
            pk1 = *(const float4*)&Kg[g + 4];
            pv0 = *(const float4*)&Vg[g];
            pv1 = *(const float4*)&Vg[g + 4];
        }

        {
            const bool diag = (kt == qb);   // only the diagonal tile masks
            float s[32];
            #pragma unroll
            for (int j = 0; j < 32; ++j) {
                const float4* kr = (const float4*)&Ks[j][half * 32];
                float acc = 0.f;
                #pragma unroll
                for (int ii = 0; ii < 8; ++ii) {
                    const float4 kx = kr[ii];
                    const float4 qx = q4[ii];
                    acc = fmaf(qx.x, kx.x, acc);
                    acc = fmaf(qx.y, kx.y, acc);
                    acc = fmaf(qx.z, kx.z, acc);
                    acc = fmaf(qx.w, kx.w, acc);
                }
                acc += __shfl_xor(acc, 32);   // sum the two 32-dim halves
                s[j] = (!diag || j <= row) ? acc * SM_SCALE : -3.0e38f;
            }

            float mnew = m;
            #pragma unroll
            for (int j = 0; j < 32; ++j) mnew = fmaxf(mnew, s[j]);

            const float corr = __expf(m - mnew);   // first tile: exp(-huge)=0
            l *= corr;
            #pragma unroll
            for (int i = 0; i < 8; ++i) {
                o4[i].x *= corr; o4[i].y *= corr;
                o4[i].z *= corr; o4[i].w *= corr;
            }

            #pragma unroll
            for (int j = 0; j < 32; ++j) {
                const float p = __expf(s[j] - mnew);
                l += p;
                const float4* vr = (const float4*)&Vs[j][half * 32];
                #pragma unroll
                for (int ii = 0; ii < 8; ++ii) {
                    const float4 vx = vr[ii];
                    o4[ii].x = fmaf(p, vx.x, o4[ii].x);
                    o4[ii].y = fmaf(p, vx.y, o4[ii].y);
                    o4[ii].z = fmaf(p, vx.z, o4[ii].z);
                    o4[ii].w = fmaf(p, vx.w, o4[ii].w);
                }
            }
            m = mnew;
        }

        __syncthreads();                // all waves done with tile kt

        if (kt + 1 < ntiles) {          // commit prefetched tile kt+1
            *(float4*)&Ks[sr][sc]     = pk0;
            *(float4*)&Ks[sr][sc + 4] = pk1;
            *(float4*)&Vs[sr][sc]     = pv0;
            *(float4*)&Vs[sr][sc + 4] = pv1;
        }
    }

    const float inv = 1.f / l;
    float* orow = out + (size_t)t * Q_COLS + h * HD + half * 32;
    #pragma unroll
    for (int i = 0; i < 8; ++i) {
        float4 v = o4[i];
        v.x *= inv; v.y *= inv; v.z *= inv; v.w *= inv;
        *(float4*)&orow[i * 4] = v;
    }
}

// ---------------------------------------------------------------------------
extern "C" void kernel_launch(void* const* d_in, const int* in_sizes, int n_in,
                              void* d_out, int out_size, void* d_ws, size_t ws_size,
                              hipStream_t stream) {
    const float* hidden    = (const float*)d_in[0];
    const int*   positions = (const int*)d_in[1];
    const float* w_qkv     = (const float*)d_in[2];
    const float* w_o       = (const float*)d_in[3];
    float* out = (float*)d_out;

    float* qkv  = (float*)d_ws;                          // [T, 3072] 25.2 MB
    float* attn = qkv + (size_t)T_SEQ * QKV_N;           // [T, 2048] 16.8 MB

    // 1) QKV projection: qkv = hidden @ w_qkv^T
    gemm_nt<<<dim3(QKV_N / 128, T_SEQ / 128), 256, 0, stream>>>(
        hidden, w_qkv, qkv, T_SEQ, QKV_N, HIDDEN);

    // 2) RoPE on q and k, in place
    rope_kernel<<<(T_SEQ * 40 * 32 + 255) / 256, 256, 0, stream>>>(qkv, positions);

    // 3) causal GQA attention -> attn [T, NH*HD]
    attn_fp32<<<dim3(T_SEQ / 32, NKV), 256, 0, stream>>>(qkv, attn);

    // 4) output projection: out = attn @ w_o^T
    gemm_nt<<<dim3(HIDDEN / 128, T_SEQ / 128), 256, 0, stream>>>(
        attn, w_o, out, T_SEQ, HIDDEN, Q_COLS);
}